// Round 3
// baseline (8187.434 us; speedup 1.0000x reference)
//
#include <hip/hip_runtime.h>
#include <math.h>

// Problem constants
#define TT 512
#define BB 64
#define EE 300
#define HD 256
#define KK 20
#define NG 1024        // gate rows per direction
#define RG 4           // row-groups per direction
#define RPB 16         // rows per block
#define DPB 32         // dims per block
#define HS 260         // LDS h row stride (floats), padded
#define LDS_FLOATS (RPB * HS)   // 4160 floats = 16640 B (h slice only; W lives in VGPRs)

// Relaxed agent-scope atomics = cache-bypassing LLC ops (no fences anywhere;
// W/P stay cache-resident). Proven correct in prior rounds (absmax 0).
__device__ __forceinline__ int ldg_llc_i(const int* p) {
    return __hip_atomic_load(p, __ATOMIC_RELAXED, __HIP_MEMORY_SCOPE_AGENT);
}
__device__ __forceinline__ void stg_llc_i(int* p, int v) {
    __hip_atomic_store(p, v, __ATOMIC_RELAXED, __HIP_MEMORY_SCOPE_AGENT);
}
__device__ __forceinline__ unsigned long long ldg_llc_u64(const unsigned long long* p) {
    return __hip_atomic_load(p, __ATOMIC_RELAXED, __HIP_MEMORY_SCOPE_AGENT);
}
__device__ __forceinline__ void stg_llc_u64(unsigned long long* p, unsigned long long v) {
    __hip_atomic_store(p, v, __ATOMIC_RELAXED, __HIP_MEMORY_SCOPE_AGENT);
}

// branchless 4-way select (compile-time value indices only)
__device__ __forceinline__ float mux4(int t, float x0, float x1, float x2, float x3) {
    const bool b0 = (t & 1) != 0, b1 = (t & 2) != 0;
    const float lo = b0 ? x1 : x0;
    const float hi = b0 ? x3 : x2;
    return b1 ? hi : lo;
}

// ============================================================
// K1: fused embedding-gather + input projection GEMM (fp32)
// P layout: [slot][row(64)][gate(1024)] (gate innermost).  (unchanged, proven)
// ============================================================
__global__ __launch_bounds__(256) void proj_kernel(
    const int* __restrict__ sentence, const float* __restrict__ embed,
    const float* __restrict__ Wf_ih, const float* __restrict__ bf,
    const float* __restrict__ Wb_ih, const float* __restrict__ bb,
    float* __restrict__ Pf, float* __restrict__ Pb, int t0f, int t0b)
{
    __shared__ float As[32][BB];
    __shared__ float Ws[32][64];
    const int s   = blockIdx.x;
    const int gb  = blockIdx.y;
    const int dir = gb >> 4;
    const int g0  = (gb & 15) * 64;
    const int tg  = dir ? (t0b + s) : (t0f + s);
    const int tid = threadIdx.x;
    const int tx = tid & 15, ty = tid >> 4;

    const int lrow = tid >> 2;
    const int kq   = tid & 3;
    const int word = sentence[lrow * TT + tg];
    const float* arow = embed + (size_t)word * EE;
    const float* Wih  = dir ? Wb_ih : Wf_ih;
    const float* bias = dir ? bb : bf;
    const float* wrow = Wih + (size_t)(g0 + lrow) * EE;

    float acc[4][4] = {};
    for (int k0 = 0; k0 < EE; k0 += 32) {
        __syncthreads();
        #pragma unroll
        for (int u = 0; u < 8; ++u) {
            const int k  = kq * 8 + u;
            const int kk = k0 + k;
            const bool ok = (kk < EE);
            As[k][lrow] = ok ? arow[kk] : 0.f;
            Ws[k][lrow] = ok ? wrow[kk] : 0.f;
        }
        __syncthreads();
        #pragma unroll
        for (int k = 0; k < 32; ++k) {
            const float4 a = *(const float4*)&As[k][ty * 4];
            const float4 w = *(const float4*)&Ws[k][tx * 4];
            acc[0][0] += a.x*w.x; acc[0][1] += a.x*w.y; acc[0][2] += a.x*w.z; acc[0][3] += a.x*w.w;
            acc[1][0] += a.y*w.x; acc[1][1] += a.y*w.y; acc[1][2] += a.y*w.z; acc[1][3] += a.y*w.w;
            acc[2][0] += a.z*w.x; acc[2][1] += a.z*w.y; acc[2][2] += a.z*w.z; acc[2][3] += a.z*w.w;
            acc[3][0] += a.w*w.x; acc[3][1] += a.w*w.y; acc[3][2] += a.w*w.z; acc[3][3] += a.w*w.w;
        }
    }
    float* Pd = (dir ? Pb : Pf) + (size_t)s * BB * NG;
    const float4 bv = *(const float4*)&bias[g0 + tx * 4];
    #pragma unroll
    for (int i = 0; i < 4; ++i) {
        float4 v;
        v.x = acc[i][0] + bv.x; v.y = acc[i][1] + bv.y;
        v.z = acc[i][2] + bv.z; v.w = acc[i][3] + bv.w;
        *(float4*)(Pd + (size_t)(ty * 4 + i) * NG + g0 + tx * 4) = v;
    }
}

// ============================================================
// K2: 2D-partitioned bidirectional LSTM, W_hh in REGISTERS (persistent-RNN).
// 64 blocks x 256 threads. blk&7 = domain (dir*4 + row-group i); dim-group
// j = blk>>3. Block owns 16 rows x 32 dims. Lane = (d = (lane>>3) dim,
// s = lane&7 k-slice of 32 k). Thread holds W[4 gates][its dim][32 k] = 128
// VGPRs, ROTATED by s: both the LDS h offset (q+s)&7 and the register index
// are compile-time static, and the 8 s-lanes hit 8 distinct bank-quads
// (conflict-free; 8-way same-address broadcast across d).
// Per step: poll flags -> stage 16 KB h [r][k] (LLC->LDS) -> TWO 8-row passes
// {1024 FMA partials acc[4][8] -> 3-round __shfl_xor butterfly -> mux4 extract}
// -> cell math (rows 2s,2s+1) -> publish (LLC) -> flag.
// Two passes keep live VGPRs ~175 (vs 230 single-pass) — RA hardening.
// ============================================================
__global__ __launch_bounds__(256, 1) void lstm_kernel(
    const float* __restrict__ Pf, const float* __restrict__ Pb,
    const float* __restrict__ Wf_hh, const float* __restrict__ Wb_hh,
    const int* __restrict__ lengths,
    float* __restrict__ HF, float* __restrict__ HB,
    float* __restrict__ hx,      // [parity][dir][rg][dim 256][row 16]
    float* __restrict__ cbuf,    // [dir][dim 256][row 64]
    int* __restrict__ flags,     // [dir*4+rg][16] (one 64B line per domain)
    int step0, int nsteps)
{
    __shared__ float lds[LDS_FLOATS];
    const int blk    = blockIdx.x;
    const int domain = blk & 7;          // dir*4 + i  (XCD residue)
    const int j      = blk >> 3;         // dim-group 0..7
    const int dir    = domain >> 2;
    const int i      = domain & 3;       // row-group
    const int tid    = threadIdx.x;
    const int w      = tid >> 6;         // wave 0..3
    const int lane   = tid & 63;
    const int d      = lane >> 3;        // dim-within-wave 0..7
    const int s      = lane & 7;         // k-slice 0..7
    const int dg     = j * DPB + w * 8 + d;   // global dim 0..255
    const int gr0    = i * RPB + 2 * s;       // this lane's even output row

    const float* Whh = dir ? Wb_hh : Wf_hh;
    const float* P   = dir ? Pb : Pf;
    float* Hout = dir ? HB : HF;
    int* myflags = flags + domain * 16;
    const int len0 = lengths[gr0], len1 = lengths[gr0 + 1];

    // ---- W_hh slice -> registers, rotated by s:
    // wreg[g][q] = W[g*256+dg][k = s*32 + ((q+s)&7)*4 .. +3]
    float4 wreg[4][8];
    #pragma unroll
    for (int g = 0; g < 4; ++g) {
        const float* wrow = Whh + (size_t)(g * HD + dg) * HD;
        #pragma unroll
        for (int q = 0; q < 8; ++q) {
            const int m = (q + s) & 7;
            wreg[g][q] = *(const float4*)&wrow[s * 32 + m * 4];
        }
    }
    // per-lane LDS h-read offsets (floats): conflict-free across s for any (r,q)
    int hoff[8];
    #pragma unroll
    for (int q = 0; q < 8; ++q) hoff[q] = s * 32 + (((q + s) & 7) << 2);

    // ---- cell state (this lane's two rows)
    const float2 cin = *(const float2*)&cbuf[((size_t)dir * HD + dg) * BB + gr0];
    float c0 = cin.x, c1 = cin.y;
    __syncthreads();

    for (int u = 0; u < nsteps; ++u) {
        const int gs   = step0 + u;
        const int p    = dir ? (TT - 1 - gs) : gs;
        const int slot = dir ? (nsteps - 1 - u) : u;

        // P terms (h-independent): 8 loads issued before the wait
        const float* Pp = P + (size_t)slot * BB * NG + (size_t)gr0 * NG + dg;
        const float pi0 = Pp[0],      pf0 = Pp[256],      pg0 = Pp[512],      po0 = Pp[768];
        const float pi1 = Pp[NG + 0], pf1 = Pp[NG + 256], pg1 = Pp[NG + 512], po1 = Pp[NG + 768];

        // wait: all 8 peers (dim-groups) of this domain finished step gs-1
        if (tid < 64) {
            const int* fl = myflags + (tid & 7);
            while (true) {
                const int v = ldg_llc_i(fl);
                if (__all(v >= gs)) break;
            }
        }
        __syncthreads();

        // stage h slice (16 KB) LLC -> LDS, transposing [k][r] -> [r][k]
        {
            const unsigned long long* src = (const unsigned long long*)
                (hx + ((size_t)(((gs + 1) & 1) * 2 + dir) * RG + i) * (HD * RPB));
            const int kbase = tid >> 3, rp = tid & 7;
            #pragma unroll
            for (int it = 0; it < 8; ++it) {
                const int k = kbase + 32 * it;
                const unsigned long long v = ldg_llc_u64(&src[k * 8 + rp]);
                union { unsigned long long u; float f[2]; } cv; cv.u = v;
                lds[(2 * rp) * HS + k]     = cv.f[0];
                lds[(2 * rp + 1) * HS + k] = cv.f[1];
            }
        }
        __syncthreads();

        // ---- pass A: rows 0..7 ----
        float aA0[4], aA1[4];
        {
            float acc[4][8];
            #pragma unroll
            for (int g = 0; g < 4; ++g)
                #pragma unroll
                for (int r = 0; r < 8; ++r) acc[g][r] = 0.f;
            #pragma unroll
            for (int r = 0; r < 8; ++r) {
                #pragma unroll
                for (int q = 0; q < 8; ++q) {
                    const float4 h4 = *(const float4*)&lds[r * HS + hoff[q]];
                    #pragma unroll
                    for (int g = 0; g < 4; ++g) {
                        acc[g][r] = fmaf(wreg[g][q].x, h4.x, acc[g][r]);
                        acc[g][r] = fmaf(wreg[g][q].y, h4.y, acc[g][r]);
                        acc[g][r] = fmaf(wreg[g][q].z, h4.z, acc[g][r]);
                        acc[g][r] = fmaf(wreg[g][q].w, h4.w, acc[g][r]);
                    }
                }
            }
            // butterfly over the 8 s-lanes (same d): full sums on every lane
            #pragma unroll
            for (int g = 0; g < 4; ++g)
                #pragma unroll
                for (int r = 0; r < 8; ++r) {
                    acc[g][r] += __shfl_xor(acc[g][r], 1);
                    acc[g][r] += __shfl_xor(acc[g][r], 2);
                    acc[g][r] += __shfl_xor(acc[g][r], 4);
                }
            #pragma unroll
            for (int g = 0; g < 4; ++g) {
                aA0[g] = mux4(s & 3, acc[g][0], acc[g][2], acc[g][4], acc[g][6]);
                aA1[g] = mux4(s & 3, acc[g][1], acc[g][3], acc[g][5], acc[g][7]);
            }
        }
        // ---- pass B: rows 8..15 ----
        float a0[4], a1[4];
        {
            float acc[4][8];
            #pragma unroll
            for (int g = 0; g < 4; ++g)
                #pragma unroll
                for (int r = 0; r < 8; ++r) acc[g][r] = 0.f;
            #pragma unroll
            for (int r = 0; r < 8; ++r) {
                #pragma unroll
                for (int q = 0; q < 8; ++q) {
                    const float4 h4 = *(const float4*)&lds[(r + 8) * HS + hoff[q]];
                    #pragma unroll
                    for (int g = 0; g < 4; ++g) {
                        acc[g][r] = fmaf(wreg[g][q].x, h4.x, acc[g][r]);
                        acc[g][r] = fmaf(wreg[g][q].y, h4.y, acc[g][r]);
                        acc[g][r] = fmaf(wreg[g][q].z, h4.z, acc[g][r]);
                        acc[g][r] = fmaf(wreg[g][q].w, h4.w, acc[g][r]);
                    }
                }
            }
            #pragma unroll
            for (int g = 0; g < 4; ++g)
                #pragma unroll
                for (int r = 0; r < 8; ++r) {
                    acc[g][r] += __shfl_xor(acc[g][r], 1);
                    acc[g][r] += __shfl_xor(acc[g][r], 2);
                    acc[g][r] += __shfl_xor(acc[g][r], 4);
                }
            #pragma unroll
            for (int g = 0; g < 4; ++g) {
                const float b0 = mux4(s & 3, acc[g][0], acc[g][2], acc[g][4], acc[g][6]);
                const float b1 = mux4(s & 3, acc[g][1], acc[g][3], acc[g][5], acc[g][7]);
                a0[g] = (s < 4) ? aA0[g] : b0;
                a1[g] = (s < 4) ? aA1[g] : b1;
            }
        }

        // cell math (both rows)
        const float ig0 = 1.f / (1.f + expf(-(a0[0] + pi0)));
        const float fg0 = 1.f / (1.f + expf(-(a0[1] + pf0)));
        const float og0 = 1.f / (1.f + expf(-(a0[3] + po0)));
        const float gt0 = tanhf(a0[2] + pg0);
        float cn0 = fg0 * c0 + ig0 * gt0;
        float hn0 = og0 * tanhf(cn0);
        const float ig1 = 1.f / (1.f + expf(-(a1[0] + pi1)));
        const float fg1 = 1.f / (1.f + expf(-(a1[1] + pf1)));
        const float og1 = 1.f / (1.f + expf(-(a1[3] + po1)));
        const float gt1 = tanhf(a1[2] + pg1);
        float cn1 = fg1 * c1 + ig1 * gt1;
        float hn1 = og1 * tanhf(cn1);
        if (dir) {                  // bwd rows inactive until p < len
            const bool v0 = (p < len0), v1 = (p < len1);
            c0 = v0 ? cn0 : c0;  hn0 = v0 ? hn0 : 0.f;
            c1 = v1 ? cn1 : c1;  hn1 = v1 ? hn1 : 0.f;
        } else {
            c0 = cn0; c1 = cn1;
        }

        // publish h (2 KB/block): packed 8B atomic store to LLC
        {
            union { float f[2]; unsigned long long u; } pk;
            pk.f[0] = hn0; pk.f[1] = hn1;
            unsigned long long* dst = (unsigned long long*)
                (hx + ((size_t)((gs & 1) * 2 + dir) * RG + i) * (HD * RPB) + dg * RPB + 2 * s);
            stg_llc_u64(dst, pk.u);
        }
        // H for emissions: [t][d][b] layout, float2 per thread
        {
            float2 hv; hv.x = hn0; hv.y = hn1;
            *(float2*)&Hout[((size_t)p * HD + dg) * BB + gr0] = hv;
        }

        __syncthreads();   // vmcnt(0): h complete at LLC before flag
        if (tid == 0) stg_llc_i(&myflags[j], gs + 1);
    }

    float2 cout; cout.x = c0; cout.y = c1;
    *(float2*)&cbuf[((size_t)dir * HD + dg) * BB + gr0] = cout;
}

// ============================================================
// K3: emissions = [hf|hb] @ W_out^T + b_out -> emis[t][b][20]
// H layout [t][d][b].  (unchanged, proven)
// ============================================================
__global__ __launch_bounds__(256) void emis_kernel(
    const float* __restrict__ HF, const float* __restrict__ HB,
    const float* __restrict__ W_out, const float* __restrict__ b_out,
    float* __restrict__ emis)
{
    const int t = blockIdx.x;
    const int b = threadIdx.x & 63;
    int jg = threadIdx.x >> 6;
    jg = __builtin_amdgcn_readfirstlane(jg);

    float acc[5];
    #pragma unroll
    for (int u = 0; u < 5; ++u) acc[u] = b_out[jg + 4 * u];

    const float* hf = HF + (size_t)t * HD * BB + b;
    const float* hb = HB + (size_t)t * HD * BB + b;
    for (int k = 0; k < HD; ++k) {
        const float hv = hf[(size_t)k * BB];
        #pragma unroll
        for (int u = 0; u < 5; ++u)
            acc[u] = fmaf(hv, W_out[(size_t)(jg + 4 * u) * 512 + k], acc[u]);
    }
    for (int k = 0; k < HD; ++k) {
        const float hv = hb[(size_t)k * BB];
        #pragma unroll
        for (int u = 0; u < 5; ++u)
            acc[u] = fmaf(hv, W_out[(size_t)(jg + 4 * u) * 512 + HD + k], acc[u]);
    }
    #pragma unroll
    for (int u = 0; u < 5; ++u)
        emis[((size_t)t * BB + b) * KK + jg + 4 * u] = acc[u];
}

// ============================================================
// K4: Viterbi per batch row; exact first-max argmax; bp in LDS. (unchanged)
// ============================================================
__global__ __launch_bounds__(64) void viterbi_kernel(
    const float* __restrict__ emis, const int* __restrict__ lengths,
    const float* __restrict__ trans, const int* __restrict__ stop_id_p,
    float* __restrict__ out)
{
    __shared__ float tr[KK * KK];
    __shared__ float delta[KK], nd[KK];
    __shared__ unsigned char bp[TT][KK];
    const int b = blockIdx.x;
    const int tid = threadIdx.x;
    for (int i = tid; i < KK * KK; i += 64) tr[i] = trans[i];
    if (tid < KK) delta[tid] = 0.f;
    const int len = lengths[b];
    __syncthreads();

    for (int t = 0; t < TT; ++t) {
        if (tid < KK) {
            if (t < len) {
                float best = delta[0] + tr[tid * KK + 0];
                int am = 0;
                for (int p2 = 1; p2 < KK; ++p2) {
                    const float v = delta[p2] + tr[tid * KK + p2];
                    if (v > best) { best = v; am = p2; }
                }
                nd[tid] = best + emis[((size_t)t * BB + b) * KK + tid];
                bp[t][tid] = (unsigned char)am;
            } else {
                nd[tid] = delta[tid];
                bp[t][tid] = (unsigned char)tid;
            }
        }
        __syncthreads();
        if (tid < KK) delta[tid] = nd[tid];
        __syncthreads();
    }

    if (tid == 0) {
        const int stop_id = *stop_id_p;
        float best = delta[0] + tr[stop_id * KK + 0];
        int bl = 0;
        for (int jx = 1; jx < KK; ++jx) {
            const float v = delta[jx] + tr[stop_id * KK + jx];
            if (v > best) { best = v; bl = jx; }
        }
        out[b] = best;
        float* pout = out + BB + (size_t)b * (TT + 1);
        pout[TT] = (float)bl;
        int tag = bl;
        for (int t = TT - 1; t >= 0; --t) {
            tag = bp[t][tag];
            pout[t] = (float)tag;
        }
    }
}

// ============================================================
extern "C" void kernel_launch(void* const* d_in, const int* in_sizes, int n_in,
                              void* d_out, int out_size, void* d_ws, size_t ws_size,
                              hipStream_t stream) {
    const int*   sentence = (const int*)d_in[0];
    const int*   lengths  = (const int*)d_in[1];
    const int*   stop_id  = (const int*)d_in[3];
    const float* embed    = (const float*)d_in[4];
    const float* Wf_ih    = (const float*)d_in[5];
    const float* Wf_hh    = (const float*)d_in[6];
    const float* bf       = (const float*)d_in[7];
    const float* Wb_ih    = (const float*)d_in[8];
    const float* Wb_hh    = (const float*)d_in[9];
    const float* bb       = (const float*)d_in[10];
    const float* W_out    = (const float*)d_in[11];
    const float* b_out    = (const float*)d_in[12];
    const float* trans    = (const float*)d_in[13];
    float* out = (float*)d_out;

    const size_t hf_elems   = (size_t)TT * HD * BB;
    const size_t emis_elems = (size_t)TT * BB * KK;
    const size_t hx_elems   = (size_t)2 * 2 * RG * HD * RPB;  // 65536
    const size_t cbuf_elems = (size_t)2 * HD * BB;            // 32768
    const size_t flag_elems = (size_t)8 * 16;
    const size_t fixed_bytes = (2 * hf_elems + emis_elems + hx_elems + cbuf_elems + flag_elems) * 4;

    int CH = 0;
    const int cands[6] = {256, 128, 64, 32, 16, 8};
    for (int i = 0; i < 6; ++i) {
        const size_t need = fixed_bytes + 2ull * cands[i] * BB * NG * 4;
        if (need <= ws_size) { CH = cands[i]; break; }
    }
    if (CH == 0) return;

    float* Pf    = (float*)d_ws;
    float* Pb    = Pf + (size_t)CH * BB * NG;
    float* HF    = Pb + (size_t)CH * BB * NG;
    float* HB    = HF + hf_elems;
    float* emis  = HB + hf_elems;
    float* hx    = emis + emis_elems;
    float* cbuf  = hx + hx_elems;
    int*   flags = (int*)(cbuf + cbuf_elems);

    // zero hx (both parities), cbuf, flags — contiguous region
    hipMemsetAsync(hx, 0, (hx_elems + cbuf_elems + flag_elems) * 4, stream);

    const int nch = TT / CH;
    for (int c = 0; c < nch; ++c) {
        const int t0f = c * CH;
        const int t0b = TT - (c + 1) * CH;
        proj_kernel<<<dim3(CH, 32), 256, 0, stream>>>(
            sentence, embed, Wf_ih, bf, Wb_ih, bb, Pf, Pb, t0f, t0b);
        lstm_kernel<<<dim3(64), 256, 0, stream>>>(
            Pf, Pb, Wf_hh, Wb_hh, lengths, HF, HB, hx, cbuf, flags, c * CH, CH);
    }
    emis_kernel<<<dim3(TT), 256, 0, stream>>>(HF, HB, W_out, b_out, emis);
    viterbi_kernel<<<dim3(BB), 64, 0, stream>>>(emis, lengths, trans, stop_id, out);
}